// Round 14
// baseline (312.291 us; speedup 1.0000x reference)
//
#include <hip/hip_runtime.h>
#include <math.h>

#define S_LEN 4096
#define HIDDEN 2048
#define N_HEADS 16
#define N_KV 4
#define HEAD_DIM 128
#define QDIM 2048
#define KDIM 512
#define QKVD 3072
// 1/sqrt(128) * log2(e): scores computed in log2 domain (exp2 needs only a sub).
// NOTE (R12 lesson): norm is over the FLAT 2048 dims, so per-head |s| can reach ~130
// in log2 domain -- exp2 without max subtraction can overflow f32. Defer-max stays.
#define QSCALE 0.1275174486f

typedef __bf16 bf16x8 __attribute__((ext_vector_type(8)));
typedef float f32x4 __attribute__((ext_vector_type(4)));
typedef float f32x16 __attribute__((ext_vector_type(16)));

__device__ __forceinline__ unsigned short f2bf(float x) {
  union { float f; unsigned u; } v; v.f = x;
  unsigned r = v.u + 0x7fffu + ((v.u >> 16) & 1u);
  return (unsigned short)(r >> 16);
}
__device__ __forceinline__ float bf2f(unsigned short u) {
  union { unsigned u; float f; } v; v.u = ((unsigned)u) << 16;
  return v.f;
}

__device__ __forceinline__ float wave_sum(float x) {
#pragma unroll
  for (int w = 32; w >= 1; w >>= 1) x += __shfl_xor(x, w);
  return x;
}

__device__ __forceinline__ void cvt4(const float* __restrict__ s,
                                     unsigned short* __restrict__ d, int i) {
  float4 v = reinterpret_cast<const float4*>(s)[i];
  ushort4 o;
  o.x = f2bf(v.x); o.y = f2bf(v.y); o.z = f2bf(v.z); o.w = f2bf(v.w);
  reinterpret_cast<ushort4*>(d)[i] = o;
}

// ---------------- fused prep: all weight/input converts + RoPE table ----------------
__global__ __launch_bounds__(256) void k_prep(
    const float* __restrict__ hs, const float* __restrict__ wq, const float* __restrict__ wk,
    const float* __restrict__ wv, const float* __restrict__ wo,
    unsigned short* __restrict__ Xb, unsigned short* __restrict__ Wqkv,
    unsigned short* __restrict__ Wob, float* __restrict__ cosT, float* __restrict__ sinT) {
  const int NHS = (S_LEN * HIDDEN) / 4;
  const int NWQ = (QDIM * HIDDEN) / 4;
  const int NWK = (KDIM * HIDDEN) / 4;
  const int NWV = (KDIM * HIDDEN) / 4;
  const int NWO = (HIDDEN * QDIM) / 4;
  const int NRT = S_LEN * 64;
  const int TOT = NHS + NWQ + NWK + NWV + NWO + NRT;
  const int stride = gridDim.x * 256;
  for (int i = blockIdx.x * 256 + threadIdx.x; i < TOT; i += stride) {
    int j = i;
    if (j < NHS) { cvt4(hs, Xb, j); continue; }
    j -= NHS;
    if (j < NWQ) { cvt4(wq, Wqkv, j); continue; }
    j -= NWQ;
    if (j < NWK) { cvt4(wk, Wqkv + (size_t)QDIM * HIDDEN, j); continue; }
    j -= NWK;
    if (j < NWV) { cvt4(wv, Wqkv + (size_t)(QDIM + KDIM) * HIDDEN, j); continue; }
    j -= NWV;
    if (j < NWO) { cvt4(wo, Wob, j); continue; }
    j -= NWO;
    int s = j >> 6, d = j & 63;
    float inv = powf(10000.0f, -(float)(2 * d) * (1.0f / 128.0f));
    float f = (float)s * inv;
    cosT[j] = cosf(f);
    sinT[j] = sinf(f);
  }
}

// ---------------- GEMM (R8 best-measured): BK=64, counted vmcnt, swizzled LDS --------
#define GKT (HIDDEN / 64)

template <int BF16OUT>
__global__ __launch_bounds__(256, 2) void k_gemm(
    const unsigned short* __restrict__ A, const unsigned short* __restrict__ B,
    void* __restrict__ Cv, int N) {
  __shared__ char ldsb[65536];
  const int tid = threadIdx.x;
  const int w = tid >> 6, lane = tid & 63;
  const int l15 = lane & 15, g16 = lane >> 4;
  const int wm = w >> 1, wn = w & 1;
  const unsigned nwg = gridDim.x * gridDim.y;
  const unsigned wg = blockIdx.y * gridDim.x + blockIdx.x;
  const unsigned cpx = nwg >> 3;
  const unsigned swz = (wg & 7) * cpx + (wg >> 3);
  const int bx = swz % gridDim.x, by = swz / gridDim.x;
  const int brow = by * 128, bcol = bx * 128;
  const char* Abp = (const char*)(A + (size_t)brow * HIDDEN);
  const char* Bbp = (const char*)(B + (size_t)bcol * HIDDEN);

#define GSTAGE(bi, kt)                                                              \
  {                                                                                 \
    _Pragma("unroll")                                                               \
    for (int j = 0; j < 4; ++j) {                                                   \
      const int slot = w * 256 + j * 64 + lane;                                     \
      const int r = slot >> 3;                                                      \
      const int cb = (slot & 7) * 16;                                               \
      const char* srcA = Abp + (size_t)r * (2 * HIDDEN) + (kt) * 128 +              \
                         (cb ^ ((r & 7) << 4));                                     \
      __builtin_amdgcn_global_load_lds(                                             \
          (const __attribute__((address_space(1))) void*)srcA,                      \
          (__attribute__((address_space(3))) void*)(ldsb + (bi)*16384 + slot * 16), \
          16, 0, 0);                                                                \
      const char* srcB = Bbp + (size_t)r * (2 * HIDDEN) + (kt) * 128 +              \
                         (cb ^ ((r & 7) << 4));                                     \
      __builtin_amdgcn_global_load_lds(                                             \
          (const __attribute__((address_space(1))) void*)srcB,                      \
          (__attribute__((address_space(3))) void*)(ldsb + 32768 + (bi)*16384 +     \
                                                    slot * 16),                     \
          16, 0, 0);                                                                \
    }                                                                               \
  }

  f32x4 acc[4][4] = {};

  GSTAGE(0, 0)
  GSTAGE(1, 1)
  asm volatile("s_waitcnt vmcnt(8)" ::: "memory");
  __builtin_amdgcn_s_barrier();

  for (int kt = 0; kt < GKT; ++kt) {
    const char* Al = ldsb + (kt & 1) * 16384;
    const char* Bl = ldsb + 32768 + (kt & 1) * 16384;
    bf16x8 a[4][2], b[4][2];
#pragma unroll
    for (int fm = 0; fm < 4; ++fm) {
      const int r = wm * 64 + fm * 16 + l15;
#pragma unroll
      for (int kh = 0; kh < 2; ++kh)
        a[fm][kh] = *reinterpret_cast<const bf16x8*>(
            Al + r * 128 + ((kh * 64 + g16 * 16) ^ ((r & 7) << 4)));
    }
#pragma unroll
    for (int fn = 0; fn < 4; ++fn) {
      const int r = wn * 64 + fn * 16 + l15;
#pragma unroll
      for (int kh = 0; kh < 2; ++kh)
        b[fn][kh] = *reinterpret_cast<const bf16x8*>(
            Bl + r * 128 + ((kh * 64 + g16 * 16) ^ ((r & 7) << 4)));
    }
#pragma unroll
    for (int kh = 0; kh < 2; ++kh)
#pragma unroll
      for (int fm = 0; fm < 4; ++fm)
#pragma unroll
        for (int fn = 0; fn < 4; ++fn)
          acc[fm][fn] =
              __builtin_amdgcn_mfma_f32_16x16x32_bf16(a[fm][kh], b[fn][kh], acc[fm][fn], 0, 0, 0);
    __builtin_amdgcn_sched_barrier(0);
    __builtin_amdgcn_s_barrier();
    if (kt + 2 < GKT) GSTAGE(kt & 1, kt + 2)
    if (kt + 1 < GKT) {
      if (kt + 2 < GKT) {
        asm volatile("s_waitcnt vmcnt(8)" ::: "memory");
      } else {
        asm volatile("s_waitcnt vmcnt(0)" ::: "memory");
      }
      __builtin_amdgcn_s_barrier();
    }
  }

  const int crow = brow + wm * 64 + g16 * 4;
  const int ccol = bcol + wn * 64 + l15;
#pragma unroll
  for (int fm = 0; fm < 4; ++fm)
#pragma unroll
    for (int fn = 0; fn < 4; ++fn)
#pragma unroll
      for (int i = 0; i < 4; ++i) {
        const size_t off = (size_t)(crow + fm * 16 + i) * N + ccol + fn * 16;
        if (BF16OUT)
          ((unsigned short*)Cv)[off] = f2bf(acc[fm][fn][i]);
        else
          ((float*)Cv)[off] = acc[fm][fn][i];
      }
#undef GSTAGE
}

// ---------------- RMSNorm + RoPE + layout (bf16 QKV input) ----------------
__global__ __launch_bounds__(256) void k_norm_rope(
    const unsigned short* __restrict__ QKV, const float* __restrict__ qw,
    const float* __restrict__ kw, const float* __restrict__ cosT,
    const float* __restrict__ sinT, unsigned short* __restrict__ Q,
    unsigned short* __restrict__ Kd, unsigned short* __restrict__ Vt) {
  const int s = blockIdx.x;
  const int tid = threadIdx.x;
  const int lane = tid & 63, wave = tid >> 6;
  const unsigned short* row = QKV + (size_t)s * QKVD;
  __shared__ float sm[QDIM];
  __shared__ float red[4];

  float qv[8];
  {
    uint4 r = *reinterpret_cast<const uint4*>(row + tid * 8);
    unsigned u[4] = {r.x, r.y, r.z, r.w};
#pragma unroll
    for (int j = 0; j < 4; ++j) {
      qv[2 * j] = bf2f((unsigned short)(u[j] & 0xffff));
      qv[2 * j + 1] = bf2f((unsigned short)(u[j] >> 16));
    }
  }
  float ss = 0;
#pragma unroll
  for (int j = 0; j < 8; ++j) ss += qv[j] * qv[j];
  ss = wave_sum(ss);
  if (lane == 0) red[wave] = ss;
  __syncthreads();
  float tot = red[0] + red[1] + red[2] + red[3];
  float qs = rsqrtf(tot * (1.0f / QDIM) + 1e-5f) * QSCALE;
#pragma unroll
  for (int j = 0; j < 8; ++j) sm[tid * 8 + j] = qv[j] * qs * qw[tid * 8 + j];
  __syncthreads();
  {
    const int d0 = tid * 8;
    const int h = d0 >> 7;
    const int dh = d0 & 127;
    const int dc = dh & 63;
    const bool lo = dh < 64;
    const float sgn = lo ? -1.0f : 1.0f;
    const int po = lo ? 64 : -64;
    union { unsigned short b[8]; uint4 u; } pk;
#pragma unroll
    for (int j = 0; j < 8; ++j) {
      float c = cosT[s * 64 + dc + j];
      float sn = sinT[s * 64 + dc + j];
      float o = sm[d0 + j] * c + sgn * sm[d0 + po + j] * sn;
      pk.b[j] = f2bf(o);
    }
    *reinterpret_cast<uint4*>(Q + ((size_t)h * S_LEN + s) * HEAD_DIM + dh) = pk.u;
  }
  __syncthreads();

  float kx, ky;
  {
    unsigned kr = *reinterpret_cast<const unsigned*>(row + QDIM + tid * 2);
    kx = bf2f((unsigned short)(kr & 0xffff));
    ky = bf2f((unsigned short)(kr >> 16));
  }
  ss = kx * kx + ky * ky;
  ss = wave_sum(ss);
  if (lane == 0) red[wave] = ss;
  __syncthreads();
  tot = red[0] + red[1] + red[2] + red[3];
  float ks = rsqrtf(tot * (1.0f / KDIM) + 1e-5f);
  sm[tid * 2] = kx * ks * kw[tid * 2];
  sm[tid * 2 + 1] = ky * ks * kw[tid * 2 + 1];
  __syncthreads();
  {
    const int d0 = tid * 2;
    const int g = d0 >> 7;
    const int dh = d0 & 127;
    const int dc = dh & 63;
    const bool lo = dh < 64;
    const float sgn = lo ? -1.0f : 1.0f;
    const int po = lo ? 64 : -64;
    union { unsigned short b[2]; unsigned u; } pk;
#pragma unroll
    for (int j = 0; j < 2; ++j) {
      float c = cosT[s * 64 + dc + j];
      float sn = sinT[s * 64 + dc + j];
      float o = sm[d0 + j] * c + sgn * sm[d0 + po + j] * sn;
      pk.b[j] = f2bf(o);
    }
    *reinterpret_cast<unsigned*>(Kd + ((size_t)g * S_LEN + s) * HEAD_DIM + dh) = pk.u;
  }

  {
    unsigned vr = *reinterpret_cast<const unsigned*>(row + QDIM + KDIM + tid * 2);
    int dv = tid * 2;
    int g = dv >> 7, d = dv & 127;
    Vt[(size_t)(g * HEAD_DIM + d) * S_LEN + s] = (unsigned short)(vr & 0xffff);
    Vt[(size_t)(g * HEAD_DIM + d + 1) * S_LEN + s] = (unsigned short)(vr >> 16);
  }
}

// ---------------- Causal GQA flash attention, 32x32 MFMA (R13 + chain diet) ----------
// Identical structure/sync/layout to verified R13. Inner-loop-only changes:
// (1) max reduce as v_max3-friendly depth-3 tree (was 15-deep serial fmax chain);
// (2) rs sum as explicit pairwise tree (f32 adds not reassociable by compiler);
// (3) pf-build via permlane32_swap: one swap yields BOTH pf words (replaces
//     8 shfl_xor + 8 cndmask with 4 swaps per tile). Verified algebra:
//     swap(A0,A2) -> {l<32:A0[l], l>=32:A2[l-32]} = pf.x ; {l<32:A0[l+32], l>=32:A2[l]} = pf.z.
__global__ __launch_bounds__(256, 3) void k_attn(
    const unsigned short* __restrict__ Q, const unsigned short* __restrict__ K,
    const unsigned short* __restrict__ Vt,
    unsigned short* __restrict__ Op0, unsigned short* __restrict__ Op1,
    float* __restrict__ Mp, float* __restrict__ Lp) {
  const int bid = blockIdx.x;
  const int qt = 127 - (bid >> 3);          // heavy q-tiles first (LPT)
  const int sub = bid & 7;
  const int g = sub >> 1, half = sub & 1;
  const int NT = qt + 1, ntlo = (NT + 1) >> 1;  // kv tiles of 32
  const int t0 = half ? ntlo : 0, t1 = half ? NT : ntlo;

  const int tid = threadIdx.x;
  const int w = tid >> 6, lane = tid & 63;
  const int l31 = lane & 31, g2 = lane >> 5;
  const int h = g * 4 + w;
  const int qpos = qt * 32;

  unsigned short* __restrict__ Op = half ? Op1 : Op0;
  float* __restrict__ Mh = Mp + half * (16 * 4096);
  float* __restrict__ Lh = Lp + half * (16 * 4096);

  if (t0 >= t1) {  // empty upper half (qt==0): stats only
    if (g2 == 0) {
      Mh[h * 4096 + qpos + l31] = -1e30f;
      Lh[h * 4096 + qpos + l31] = 0.f;
    }
    return;
  }

  __shared__ char lds[2][16384];  // per buf: [0,8K) K, [8K,16K) V

  const char* Kgb = (const char*)(K + (size_t)g * S_LEN * HEAD_DIM);
  const char* Vgb = (const char*)(Vt + (size_t)g * HEAD_DIM * S_LEN);

  const bool isK = (w < 2);
  const int wj = isK ? w : (w - 2);

#define STAGE(BUFP, KV0)                                                                  \
  {                                                                                       \
    char* dstb = (BUFP);                                                                  \
    _Pragma("unroll")                                                                     \
    for (int j = 0; j < 4; ++j) {                                                         \
      if (isK) {                                                                          \
        const int r = (wj * 4 + j) * 4 + (lane >> 4);                                     \
        const char* src = Kgb + (size_t)((KV0) + r) * 256 +                               \
                          (((lane & 15) * 16) ^ ((r & 15) << 4));                         \
        __builtin_amdgcn_global_load_lds(                                                 \
            (const __attribute__((address_space(1))) void*)src,                           \
            (__attribute__((address_space(3))) void*)(dstb + (wj * 4 + j) * 1024),        \
            16, 0, 0);                                                                    \
      } else {                                                                            \
        const int r = (wj * 4 + j) * 8 + (lane >> 3);                                     \
        const int cu = ((lane & 7) * 16) ^ ((r & 7) << 4);                                \
        const int dd = 2 * r + (cu >> 6);                                                 \
        const char* src = Vgb + (size_t)dd * 8192 + (size_t)(KV0) * 2 + (cu & 63);        \
        __builtin_amdgcn_global_load_lds(                                                 \
            (const __attribute__((address_space(1))) void*)src,                           \
            (__attribute__((address_space(3))) void*)(dstb + 8192 + (wj * 4 + j) * 1024), \
            16, 0, 0);                                                                    \
      }                                                                                   \
    }                                                                                     \
  }

  STAGE(lds[0], t0 * 32)

  bf16x8 qf[8];
#pragma unroll
  for (int dc2 = 0; dc2 < 8; ++dc2)
    qf[dc2] = *reinterpret_cast<const bf16x8*>(
        Q + ((size_t)h * S_LEN + qpos + l31) * HEAD_DIM + dc2 * 16 + g2 * 8);

  f32x16 o[4] = {};
  float m = -1e30f, l = 0.f;

  for (int t = t0; t < t1; ++t) {
    char* buf = lds[(t - t0) & 1];
    __syncthreads();  // drains this buf's staging; all waves done with buf^1
    if (t + 1 < t1) STAGE(lds[(t - t0 + 1) & 1], (t + 1) * 32)
    const char* Kl = buf;
    const char* Vl = buf + 8192;
    const int kv0 = t * 32;

    f32x16 sc = {};
    __builtin_amdgcn_s_setprio(1);
#pragma unroll
    for (int dc2 = 0; dc2 < 8; ++dc2) {
      bf16x8 kf = *reinterpret_cast<const bf16x8*>(
          Kl + l31 * 256 + ((dc2 * 32 + g2 * 16) ^ ((l31 & 15) << 4)));
      sc = __builtin_amdgcn_mfma_f32_32x32x16_bf16(kf, qf[dc2], sc, 0, 0, 0);
    }
    __builtin_amdgcn_s_setprio(0);
    if (t == qt) {
#pragma unroll
      for (int reg = 0; reg < 16; ++reg) {
        int kv = kv0 + (reg & 3) + 8 * (reg >> 2) + 4 * g2;
        if (kv > qpos + l31) sc[reg] = -1e30f;
      }
    }
    // ---- max as depth-3 tree (v_max3-friendly) ----
    float x0 = fmaxf(fmaxf(sc[0], sc[1]), sc[2]);
    float x1 = fmaxf(fmaxf(sc[3], sc[4]), sc[5]);
    float x2 = fmaxf(fmaxf(sc[6], sc[7]), sc[8]);
    float x3 = fmaxf(fmaxf(sc[9], sc[10]), sc[11]);
    float x4 = fmaxf(fmaxf(sc[12], sc[13]), sc[14]);
    float pm = fmaxf(fmaxf(fmaxf(x0, x1), fmaxf(x2, x3)), fmaxf(x4, sc[15]));
    pm = fmaxf(pm, __shfl_xor(pm, 32));
    if (!__all(pm <= m + 8.f)) {  // defer-max (T13)
      float mn = fmaxf(m, pm);
      float fac = __builtin_amdgcn_exp2f(m - mn);
#pragma unroll
      for (int dc = 0; dc < 4; ++dc) o[dc] *= fac;
      l *= fac;
      m = mn;
    }
    union { __bf16 b[16]; unsigned u[8]; } P;
    float p[16];
#pragma unroll
    for (int i = 0; i < 16; ++i) {
      p[i] = __builtin_amdgcn_exp2f(sc[i] - m);
      P.b[i] = (__bf16)p[i];
    }
    // ---- rs as pairwise tree (depth 4 instead of 16) ----
    float s01 = (p[0] + p[1]) + (p[2] + p[3]);
    float s23 = (p[4] + p[5]) + (p[6] + p[7]);
    float s45 = (p[8] + p[9]) + (p[10] + p[11]);
    float s67 = (p[12] + p[13]) + (p[14] + p[15]);
    float rs = (s01 + s23) + (s45 + s67);
    rs += __shfl_xor(rs, 32);
    l += rs;
    // ---- pf build via permlane32_swap: one swap -> two output words ----
    uint4 pf[2];
#pragma unroll
    for (int c16 = 0; c16 < 2; ++c16) {
      auto r02 = __builtin_amdgcn_permlane32_swap(P.u[c16 * 4 + 0], P.u[c16 * 4 + 2],
                                                  false, false);
      auto r13 = __builtin_amdgcn_permlane32_swap(P.u[c16 * 4 + 1], P.u[c16 * 4 + 3],
                                                  false, false);
      pf[c16].x = r02[0];
      pf[c16].y = r13[0];
      pf[c16].z = r02[1];
      pf[c16].w = r13[1];
    }
    __builtin_amdgcn_s_setprio(1);
#pragma unroll
    for (int c16 = 0; c16 < 2; ++c16) {
      union { uint4 u; bf16x8 v; } cv;
      cv.u = pf[c16];
#pragma unroll
      for (int dc = 0; dc < 4; ++dc) {
        const int r = dc * 16 + (l31 >> 1);
        const int cu = (l31 & 1) * 64 + c16 * 32 + g2 * 16;
        bf16x8 vf = *reinterpret_cast<const bf16x8*>(Vl + r * 128 + (cu ^ ((r & 7) << 4)));
        o[dc] = __builtin_amdgcn_mfma_f32_32x32x16_bf16(vf, cv.v, o[dc], 0, 0, 0);
      }
    }
    __builtin_amdgcn_s_setprio(0);
  }

  if (g2 == 0) {
    Mh[h * 4096 + qpos + l31] = m;
    Lh[h * 4096 + qpos + l31] = l;
  }
#pragma unroll
  for (int dc = 0; dc < 4; ++dc)
#pragma unroll
    for (int reg = 0; reg < 16; ++reg) {
      int d = dc * 32 + (reg & 3) + 8 * (reg >> 2) + 4 * g2;
      Op[(((size_t)(h * 128 + d)) << 12) + qpos + l31] = f2bf(o[dc][reg]);
    }
#undef STAGE
}

// ---------------- combine the two kv-halves (m in log2 domain) ----------------
__global__ __launch_bounds__(256) void k_combine(
    const unsigned short* __restrict__ Op0, const unsigned short* __restrict__ Op1,
    const float* __restrict__ Mp, const float* __restrict__ Lp,
    unsigned short* __restrict__ AO) {
  const int idx = blockIdx.x * 256 + threadIdx.x;  // 65536 = 16 h * 4096 q
  const int h = idx >> 12, q = idx & 4095;
  const float m0 = Mp[h * 4096 + q], m1 = Mp[16 * 4096 + h * 4096 + q];
  const float l0 = Lp[h * 4096 + q], l1 = Lp[16 * 4096 + h * 4096 + q];
  const float mm = fmaxf(m0, m1);
  const float w0 = __builtin_amdgcn_exp2f(m0 - mm);
  const float w1 = __builtin_amdgcn_exp2f(m1 - mm);
  const float denom = w0 * l0 + w1 * l1;
  const float c0 = w0 / denom, c1 = w1 / denom;
  const bool has1 = (l1 > 0.f);
  const size_t bq = ((size_t)h * 128) << 12;
#pragma unroll
  for (int halfd = 0; halfd < 2; ++halfd) {
    float acc[64];
#pragma unroll
    for (int i = 0; i < 64; ++i) {
      const size_t off = bq + (((size_t)(halfd * 64 + i)) << 12) + q;
      float v = c0 * bf2f(Op0[off]);
      if (has1) v += c1 * bf2f(Op1[off]);
      acc[i] = v;
    }
#pragma unroll
    for (int dc = 0; dc < 8; ++dc) {
      union { unsigned short s[8]; uint4 u; } pk;
#pragma unroll
      for (int j = 0; j < 8; ++j) pk.s[j] = f2bf(acc[dc * 8 + j]);
      *reinterpret_cast<uint4*>(AO + (size_t)q * QDIM + h * 128 + halfd * 64 + dc * 8) = pk.u;
    }
  }
}

extern "C" void kernel_launch(void* const* d_in, const int* in_sizes, int n_in,
                              void* d_out, int out_size, void* d_ws, size_t ws_size,
                              hipStream_t stream) {
  const float* hs = (const float*)d_in[0];
  const float* wq = (const float*)d_in[1];
  const float* wk = (const float*)d_in[2];
  const float* wv = (const float*)d_in[3];
  const float* wo = (const float*)d_in[4];
  const float* qnw = (const float*)d_in[5];
  const float* knw = (const float*)d_in[6];
  float* out = (float*)d_out;

  char* base = (char*)d_ws;
  unsigned short* Xb = (unsigned short*)base;                  // 16.78 MB (dead after GEMM1)
  unsigned short* Qb = Xb;                                     // reuse
  unsigned short* Wqkv = (unsigned short*)(base + 16777216);   // 12.58 MB (dead after GEMM1)
  unsigned short* Kb = Wqkv;                                   // reuse (4.19 MB)
  unsigned short* Vtb = (unsigned short*)(base + 20971520);    // reuse (4.19 MB)
  float* Mp = (float*)(base + 25165824);                       // 512 KB
  float* Lp = (float*)(base + 25690112);                       // 512 KB
  unsigned short* Wob = (unsigned short*)(base + 29360128);    // 8.39 MB (live to end)
  unsigned short* QKVb = (unsigned short*)(base + 37748736);   // 25.17 MB bf16 (dead after norm)
  unsigned short* AOb = QKVb;                                  // reuse (16.78 MB)
  unsigned short* Op0 = (unsigned short*)(base + 54525952);    // 16.78 MB partial, half 0
  unsigned short* Op1 = (unsigned short*)(base + 71303168);    // 16.78 MB partial, half 1
  float* cosT = (float*)(base + 88080384);                     // 1 MB
  float* sinT = (float*)(base + 89128960);                     // 1 MB

  k_prep<<<2048, 256, 0, stream>>>(hs, wq, wk, wv, wo, Xb, Wqkv, Wob, cosT, sinT);
  k_gemm<1><<<dim3(QKVD / 128, S_LEN / 128), 256, 0, stream>>>(Xb, Wqkv, (void*)QKVb, QKVD);
  k_norm_rope<<<S_LEN, 256, 0, stream>>>(QKVb, qnw, knw, cosT, sinT, Qb, Kb, Vtb);
  k_attn<<<1024, 256, 0, stream>>>(Qb, Kb, Vtb, Op0, Op1, Mp, Lp);
  k_combine<<<256, 256, 0, stream>>>(Op0, Op1, Mp, Lp, AOb);
  k_gemm<0><<<dim3(QDIM / 128, S_LEN / 128), 256, 0, stream>>>(AOb, Wob, (void*)out, QDIM);
}

// Round 15
// 303.692 us; speedup vs baseline: 1.0283x; 1.0283x over previous
//
#include <hip/hip_runtime.h>
#include <math.h>

#define S_LEN 4096
#define HIDDEN 2048
#define N_HEADS 16
#define N_KV 4
#define HEAD_DIM 128
#define QDIM 2048
#define KDIM 512
#define QKVD 3072
// 1/sqrt(128) * log2(e): scores computed in log2 domain (exp2 needs only a sub).
// NOTE (R12 lesson): norm is over the FLAT 2048 dims, so per-head |s| can reach ~130
// in log2 domain -- exp2 without max subtraction can overflow f32. Defer-max stays.
#define QSCALE 0.1275174486f

typedef __bf16 bf16x8 __attribute__((ext_vector_type(8)));
typedef float f32x4 __attribute__((ext_vector_type(4)));
typedef float f32x16 __attribute__((ext_vector_type(16)));

__device__ __forceinline__ unsigned short f2bf(float x) {
  union { float f; unsigned u; } v; v.f = x;
  unsigned r = v.u + 0x7fffu + ((v.u >> 16) & 1u);
  return (unsigned short)(r >> 16);
}
__device__ __forceinline__ float bf2f(unsigned short u) {
  union { unsigned u; float f; } v; v.u = ((unsigned)u) << 16;
  return v.f;
}

__device__ __forceinline__ float wave_sum(float x) {
#pragma unroll
  for (int w = 32; w >= 1; w >>= 1) x += __shfl_xor(x, w);
  return x;
}

__device__ __forceinline__ void cvt4(const float* __restrict__ s,
                                     unsigned short* __restrict__ d, int i) {
  float4 v = reinterpret_cast<const float4*>(s)[i];
  ushort4 o;
  o.x = f2bf(v.x); o.y = f2bf(v.y); o.z = f2bf(v.z); o.w = f2bf(v.w);
  reinterpret_cast<ushort4*>(d)[i] = o;
}

// ---------------- fused prep: all weight/input converts + RoPE table ----------------
__global__ __launch_bounds__(256) void k_prep(
    const float* __restrict__ hs, const float* __restrict__ wq, const float* __restrict__ wk,
    const float* __restrict__ wv, const float* __restrict__ wo,
    unsigned short* __restrict__ Xb, unsigned short* __restrict__ Wqkv,
    unsigned short* __restrict__ Wob, float* __restrict__ cosT, float* __restrict__ sinT) {
  const int NHS = (S_LEN * HIDDEN) / 4;
  const int NWQ = (QDIM * HIDDEN) / 4;
  const int NWK = (KDIM * HIDDEN) / 4;
  const int NWV = (KDIM * HIDDEN) / 4;
  const int NWO = (HIDDEN * QDIM) / 4;
  const int NRT = S_LEN * 64;
  const int TOT = NHS + NWQ + NWK + NWV + NWO + NRT;
  const int stride = gridDim.x * 256;
  for (int i = blockIdx.x * 256 + threadIdx.x; i < TOT; i += stride) {
    int j = i;
    if (j < NHS) { cvt4(hs, Xb, j); continue; }
    j -= NHS;
    if (j < NWQ) { cvt4(wq, Wqkv, j); continue; }
    j -= NWQ;
    if (j < NWK) { cvt4(wk, Wqkv + (size_t)QDIM * HIDDEN, j); continue; }
    j -= NWK;
    if (j < NWV) { cvt4(wv, Wqkv + (size_t)(QDIM + KDIM) * HIDDEN, j); continue; }
    j -= NWV;
    if (j < NWO) { cvt4(wo, Wob, j); continue; }
    j -= NWO;
    int s = j >> 6, d = j & 63;
    float inv = powf(10000.0f, -(float)(2 * d) * (1.0f / 128.0f));
    float f = (float)s * inv;
    cosT[j] = cosf(f);
    sinT[j] = sinf(f);
  }
}

#define GKT (HIDDEN / 64)

// ---------------- GEMM1: 128x192 tile, 512 thr / 8 waves (2x4), BF16 out -----------
// Same verified R8 schedule (BK=64 dbuf, swizzled LDS, counted vmcnt, raw s_barrier).
// Grid = (3072/192) x (4096/128) = 16 x 32 = 512 blocks = ONE clean dispatch pass
// (vs 768-block 128x128 = 1.5 ragged passes). LDS 80KB (A 2x16K + B 2x24K) -> exactly
// 2 blocks/CU; per-kh operand reads keep VGPR ~120 so 16 waves/CU stand.
__global__ __launch_bounds__(512, 2) void k_gemm1(
    const unsigned short* __restrict__ A, const unsigned short* __restrict__ B,
    unsigned short* __restrict__ C) {
  __shared__ char ldsb[81920];  // [A0 16K][A1 16K][B0 24K][B1 24K]
  const int tid = threadIdx.x;
  const int w = tid >> 6, lane = tid & 63;
  const int l15 = lane & 15, g16 = lane >> 4;
  const int wm = w >> 2, wn = w & 3;
  const unsigned nwg = gridDim.x * gridDim.y;  // 512
  const unsigned wg = blockIdx.y * gridDim.x + blockIdx.x;
  const unsigned cpx = nwg >> 3;
  const unsigned swz = (wg & 7) * cpx + (wg >> 3);
  const int bx = swz % gridDim.x, by = swz / gridDim.x;
  const int brow = by * 128, bcol = bx * 192;
  const char* Abp = (const char*)(A + (size_t)brow * HIDDEN);
  const char* Bbp = (const char*)(B + (size_t)bcol * HIDDEN);

  // 5 loads/thread/K-tile: j=0,1 -> A (1024 slots), j=2,3,4 -> B (1536 slots).
#define GSTAGE1(bi, kt)                                                               \
  {                                                                                   \
    _Pragma("unroll")                                                                 \
    for (int j = 0; j < 5; ++j) {                                                     \
      const int s = j * 512 + tid;                                                    \
      if (j < 2) {                                                                    \
        const int r = s >> 3;                                                         \
        const int cb = (s & 7) * 16;                                                  \
        const char* src = Abp + (size_t)r * (2 * HIDDEN) + (kt) * 128 +               \
                          (cb ^ ((r & 7) << 4));                                      \
        __builtin_amdgcn_global_load_lds(                                             \
            (const __attribute__((address_space(1))) void*)src,                       \
            (__attribute__((address_space(3))) void*)(ldsb + (bi)*16384 + s * 16),    \
            16, 0, 0);                                                                \
      } else {                                                                        \
        const int sb = s - 1024;                                                      \
        const int r = sb >> 3;                                                        \
        const int cb = (sb & 7) * 16;                                                 \
        const char* src = Bbp + (size_t)r * (2 * HIDDEN) + (kt) * 128 +               \
                          (cb ^ ((r & 7) << 4));                                      \
        __builtin_amdgcn_global_load_lds(                                             \
            (const __attribute__((address_space(1))) void*)src,                       \
            (__attribute__((address_space(3))) void*)(ldsb + 32768 + (bi)*24576 +     \
                                                      sb * 16),                       \
            16, 0, 0);                                                                \
      }                                                                               \
    }                                                                                 \
  }

  f32x4 acc[4][3] = {};

  GSTAGE1(0, 0)
  GSTAGE1(1, 1)
  asm volatile("s_waitcnt vmcnt(5)" ::: "memory");  // tile0 landed; tile1 in flight
  __builtin_amdgcn_s_barrier();

  for (int kt = 0; kt < GKT; ++kt) {
    const char* Al = ldsb + (kt & 1) * 16384;
    const char* Bl = ldsb + 32768 + (kt & 1) * 24576;
#pragma unroll
    for (int kh = 0; kh < 2; ++kh) {
      bf16x8 a[4], b[3];
#pragma unroll
      for (int fm = 0; fm < 4; ++fm) {
        const int r = wm * 64 + fm * 16 + l15;
        a[fm] = *reinterpret_cast<const bf16x8*>(
            Al + r * 128 + ((kh * 64 + g16 * 16) ^ ((r & 7) << 4)));
      }
#pragma unroll
      for (int fn = 0; fn < 3; ++fn) {
        const int r = wn * 48 + fn * 16 + l15;
        b[fn] = *reinterpret_cast<const bf16x8*>(
            Bl + r * 128 + ((kh * 64 + g16 * 16) ^ ((r & 7) << 4)));
      }
#pragma unroll
      for (int fm = 0; fm < 4; ++fm)
#pragma unroll
        for (int fn = 0; fn < 3; ++fn)
          acc[fm][fn] =
              __builtin_amdgcn_mfma_f32_16x16x32_bf16(a[fm], b[fn], acc[fm][fn], 0, 0, 0);
    }
    __builtin_amdgcn_sched_barrier(0);
    __builtin_amdgcn_s_barrier();  // all reads of buf(kt) done -> safe to overwrite
    if (kt + 2 < GKT) GSTAGE1(kt & 1, kt + 2)
    if (kt + 1 < GKT) {
      if (kt + 2 < GKT) {
        asm volatile("s_waitcnt vmcnt(5)" ::: "memory");  // tile kt+1 resident
      } else {
        asm volatile("s_waitcnt vmcnt(0)" ::: "memory");  // tail drain
      }
      __builtin_amdgcn_s_barrier();
    }
  }

  const int crow = brow + wm * 64 + g16 * 4;
  const int ccol = bcol + wn * 48 + l15;
#pragma unroll
  for (int fm = 0; fm < 4; ++fm)
#pragma unroll
    for (int fn = 0; fn < 3; ++fn)
#pragma unroll
      for (int i = 0; i < 4; ++i)
        C[(size_t)(crow + fm * 16 + i) * QKVD + ccol + fn * 16] = f2bf(acc[fm][fn][i]);
#undef GSTAGE1
}

// ---------------- GEMM2 (R8 best-measured): BK=64, counted vmcnt, swizzled LDS ------
template <int BF16OUT>
__global__ __launch_bounds__(256, 2) void k_gemm(
    const unsigned short* __restrict__ A, const unsigned short* __restrict__ B,
    void* __restrict__ Cv, int N) {
  __shared__ char ldsb[65536];
  const int tid = threadIdx.x;
  const int w = tid >> 6, lane = tid & 63;
  const int l15 = lane & 15, g16 = lane >> 4;
  const int wm = w >> 1, wn = w & 1;
  const unsigned nwg = gridDim.x * gridDim.y;
  const unsigned wg = blockIdx.y * gridDim.x + blockIdx.x;
  const unsigned cpx = nwg >> 3;
  const unsigned swz = (wg & 7) * cpx + (wg >> 3);
  const int bx = swz % gridDim.x, by = swz / gridDim.x;
  const int brow = by * 128, bcol = bx * 128;
  const char* Abp = (const char*)(A + (size_t)brow * HIDDEN);
  const char* Bbp = (const char*)(B + (size_t)bcol * HIDDEN);

#define GSTAGE(bi, kt)                                                              \
  {                                                                                 \
    _Pragma("unroll")                                                               \
    for (int j = 0; j < 4; ++j) {                                                   \
      const int slot = w * 256 + j * 64 + lane;                                     \
      const int r = slot >> 3;                                                      \
      const int cb = (slot & 7) * 16;                                               \
      const char* srcA = Abp + (size_t)r * (2 * HIDDEN) + (kt) * 128 +              \
                         (cb ^ ((r & 7) << 4));                                     \
      __builtin_amdgcn_global_load_lds(                                             \
          (const __attribute__((address_space(1))) void*)srcA,                      \
          (__attribute__((address_space(3))) void*)(ldsb + (bi)*16384 + slot * 16), \
          16, 0, 0);                                                                \
      const char* srcB = Bbp + (size_t)r * (2 * HIDDEN) + (kt) * 128 +              \
                         (cb ^ ((r & 7) << 4));                                     \
      __builtin_amdgcn_global_load_lds(                                             \
          (const __attribute__((address_space(1))) void*)srcB,                      \
          (__attribute__((address_space(3))) void*)(ldsb + 32768 + (bi)*16384 +     \
                                                    slot * 16),                     \
          16, 0, 0);                                                                \
    }                                                                               \
  }

  f32x4 acc[4][4] = {};

  GSTAGE(0, 0)
  GSTAGE(1, 1)
  asm volatile("s_waitcnt vmcnt(8)" ::: "memory");
  __builtin_amdgcn_s_barrier();

  for (int kt = 0; kt < GKT; ++kt) {
    const char* Al = ldsb + (kt & 1) * 16384;
    const char* Bl = ldsb + 32768 + (kt & 1) * 16384;
    bf16x8 a[4][2], b[4][2];
#pragma unroll
    for (int fm = 0; fm < 4; ++fm) {
      const int r = wm * 64 + fm * 16 + l15;
#pragma unroll
      for (int kh = 0; kh < 2; ++kh)
        a[fm][kh] = *reinterpret_cast<const bf16x8*>(
            Al + r * 128 + ((kh * 64 + g16 * 16) ^ ((r & 7) << 4)));
    }
#pragma unroll
    for (int fn = 0; fn < 4; ++fn) {
      const int r = wn * 64 + fn * 16 + l15;
#pragma unroll
      for (int kh = 0; kh < 2; ++kh)
        b[fn][kh] = *reinterpret_cast<const bf16x8*>(
            Bl + r * 128 + ((kh * 64 + g16 * 16) ^ ((r & 7) << 4)));
    }
#pragma unroll
    for (int kh = 0; kh < 2; ++kh)
#pragma unroll
      for (int fm = 0; fm < 4; ++fm)
#pragma unroll
        for (int fn = 0; fn < 4; ++fn)
          acc[fm][fn] =
              __builtin_amdgcn_mfma_f32_16x16x32_bf16(a[fm][kh], b[fn][kh], acc[fm][fn], 0, 0, 0);
    __builtin_amdgcn_sched_barrier(0);
    __builtin_amdgcn_s_barrier();
    if (kt + 2 < GKT) GSTAGE(kt & 1, kt + 2)
    if (kt + 1 < GKT) {
      if (kt + 2 < GKT) {
        asm volatile("s_waitcnt vmcnt(8)" ::: "memory");
      } else {
        asm volatile("s_waitcnt vmcnt(0)" ::: "memory");
      }
      __builtin_amdgcn_s_barrier();
    }
  }

  const int crow = brow + wm * 64 + g16 * 4;
  const int ccol = bcol + wn * 64 + l15;
#pragma unroll
  for (int fm = 0; fm < 4; ++fm)
#pragma unroll
    for (int fn = 0; fn < 4; ++fn)
#pragma unroll
      for (int i = 0; i < 4; ++i) {
        const size_t off = (size_t)(crow + fm * 16 + i) * N + ccol + fn * 16;
        if (BF16OUT)
          ((unsigned short*)Cv)[off] = f2bf(acc[fm][fn][i]);
        else
          ((float*)Cv)[off] = acc[fm][fn][i];
      }
#undef GSTAGE
}

// ---------------- RMSNorm + RoPE + layout (bf16 QKV input) ----------------
__global__ __launch_bounds__(256) void k_norm_rope(
    const unsigned short* __restrict__ QKV, const float* __restrict__ qw,
    const float* __restrict__ kw, const float* __restrict__ cosT,
    const float* __restrict__ sinT, unsigned short* __restrict__ Q,
    unsigned short* __restrict__ Kd, unsigned short* __restrict__ Vt) {
  const int s = blockIdx.x;
  const int tid = threadIdx.x;
  const int lane = tid & 63, wave = tid >> 6;
  const unsigned short* row = QKV + (size_t)s * QKVD;
  __shared__ float sm[QDIM];
  __shared__ float red[4];

  float qv[8];
  {
    uint4 r = *reinterpret_cast<const uint4*>(row + tid * 8);
    unsigned u[4] = {r.x, r.y, r.z, r.w};
#pragma unroll
    for (int j = 0; j < 4; ++j) {
      qv[2 * j] = bf2f((unsigned short)(u[j] & 0xffff));
      qv[2 * j + 1] = bf2f((unsigned short)(u[j] >> 16));
    }
  }
  float ss = 0;
#pragma unroll
  for (int j = 0; j < 8; ++j) ss += qv[j] * qv[j];
  ss = wave_sum(ss);
  if (lane == 0) red[wave] = ss;
  __syncthreads();
  float tot = red[0] + red[1] + red[2] + red[3];
  float qs = rsqrtf(tot * (1.0f / QDIM) + 1e-5f) * QSCALE;
#pragma unroll
  for (int j = 0; j < 8; ++j) sm[tid * 8 + j] = qv[j] * qs * qw[tid * 8 + j];
  __syncthreads();
  {
    const int d0 = tid * 8;
    const int h = d0 >> 7;
    const int dh = d0 & 127;
    const int dc = dh & 63;
    const bool lo = dh < 64;
    const float sgn = lo ? -1.0f : 1.0f;
    const int po = lo ? 64 : -64;
    union { unsigned short b[8]; uint4 u; } pk;
#pragma unroll
    for (int j = 0; j < 8; ++j) {
      float c = cosT[s * 64 + dc + j];
      float sn = sinT[s * 64 + dc + j];
      float o = sm[d0 + j] * c + sgn * sm[d0 + po + j] * sn;
      pk.b[j] = f2bf(o);
    }
    *reinterpret_cast<uint4*>(Q + ((size_t)h * S_LEN + s) * HEAD_DIM + dh) = pk.u;
  }
  __syncthreads();

  float kx, ky;
  {
    unsigned kr = *reinterpret_cast<const unsigned*>(row + QDIM + tid * 2);
    kx = bf2f((unsigned short)(kr & 0xffff));
    ky = bf2f((unsigned short)(kr >> 16));
  }
  ss = kx * kx + ky * ky;
  ss = wave_sum(ss);
  if (lane == 0) red[wave] = ss;
  __syncthreads();
  tot = red[0] + red[1] + red[2] + red[3];
  float ks = rsqrtf(tot * (1.0f / KDIM) + 1e-5f);
  sm[tid * 2] = kx * ks * kw[tid * 2];
  sm[tid * 2 + 1] = ky * ks * kw[tid * 2 + 1];
  __syncthreads();
  {
    const int d0 = tid * 2;
    const int g = d0 >> 7;
    const int dh = d0 & 127;
    const int dc = dh & 63;
    const bool lo = dh < 64;
    const float sgn = lo ? -1.0f : 1.0f;
    const int po = lo ? 64 : -64;
    union { unsigned short b[2]; unsigned u; } pk;
#pragma unroll
    for (int j = 0; j < 2; ++j) {
      float c = cosT[s * 64 + dc + j];
      float sn = sinT[s * 64 + dc + j];
      float o = sm[d0 + j] * c + sgn * sm[d0 + po + j] * sn;
      pk.b[j] = f2bf(o);
    }
    *reinterpret_cast<unsigned*>(Kd + ((size_t)g * S_LEN + s) * HEAD_DIM + dh) = pk.u;
  }

  {
    unsigned vr = *reinterpret_cast<const unsigned*>(row + QDIM + KDIM + tid * 2);
    int dv = tid * 2;
    int g = dv >> 7, d = dv & 127;
    Vt[(size_t)(g * HEAD_DIM + d) * S_LEN + s] = (unsigned short)(vr & 0xffff);
    Vt[(size_t)(g * HEAD_DIM + d + 1) * S_LEN + s] = (unsigned short)(vr >> 16);
  }
}

// ---------------- Causal GQA flash attention, 32x32 MFMA (R13 exact) -----------------
__global__ __launch_bounds__(256, 3) void k_attn(
    const unsigned short* __restrict__ Q, const unsigned short* __restrict__ K,
    const unsigned short* __restrict__ Vt,
    unsigned short* __restrict__ Op0, unsigned short* __restrict__ Op1,
    float* __restrict__ Mp, float* __restrict__ Lp) {
  const int bid = blockIdx.x;
  const int qt = 127 - (bid >> 3);          // heavy q-tiles first (LPT)
  const int sub = bid & 7;
  const int g = sub >> 1, half = sub & 1;
  const int NT = qt + 1, ntlo = (NT + 1) >> 1;  // kv tiles of 32
  const int t0 = half ? ntlo : 0, t1 = half ? NT : ntlo;

  const int tid = threadIdx.x;
  const int w = tid >> 6, lane = tid & 63;
  const int l31 = lane & 31, g2 = lane >> 5;
  const int h = g * 4 + w;
  const int qpos = qt * 32;

  unsigned short* __restrict__ Op = half ? Op1 : Op0;
  float* __restrict__ Mh = Mp + half * (16 * 4096);
  float* __restrict__ Lh = Lp + half * (16 * 4096);

  if (t0 >= t1) {  // empty upper half (qt==0): stats only
    if (g2 == 0) {
      Mh[h * 4096 + qpos + l31] = -1e30f;
      Lh[h * 4096 + qpos + l31] = 0.f;
    }
    return;
  }

  __shared__ char lds[2][16384];  // per buf: [0,8K) K, [8K,16K) V

  const char* Kgb = (const char*)(K + (size_t)g * S_LEN * HEAD_DIM);
  const char* Vgb = (const char*)(Vt + (size_t)g * HEAD_DIM * S_LEN);

  const bool isK = (w < 2);
  const int wj = isK ? w : (w - 2);

#define STAGE(BUFP, KV0)                                                                  \
  {                                                                                       \
    char* dstb = (BUFP);                                                                  \
    _Pragma("unroll")                                                                     \
    for (int j = 0; j < 4; ++j) {                                                         \
      if (isK) {                                                                          \
        const int r = (wj * 4 + j) * 4 + (lane >> 4);                                     \
        const char* src = Kgb + (size_t)((KV0) + r) * 256 +                               \
                          (((lane & 15) * 16) ^ ((r & 15) << 4));                         \
        __builtin_amdgcn_global_load_lds(                                                 \
            (const __attribute__((address_space(1))) void*)src,                           \
            (__attribute__((address_space(3))) void*)(dstb + (wj * 4 + j) * 1024),        \
            16, 0, 0);                                                                    \
      } else {                                                                            \
        const int r = (wj * 4 + j) * 8 + (lane >> 3);                                     \
        const int cu = ((lane & 7) * 16) ^ ((r & 7) << 4);                                \
        const int dd = 2 * r + (cu >> 6);                                                 \
        const char* src = Vgb + (size_t)dd * 8192 + (size_t)(KV0) * 2 + (cu & 63);        \
        __builtin_amdgcn_global_load_lds(                                                 \
            (const __attribute__((address_space(1))) void*)src,                           \
            (__attribute__((address_space(3))) void*)(dstb + 8192 + (wj * 4 + j) * 1024), \
            16, 0, 0);                                                                    \
      }                                                                                   \
    }                                                                                     \
  }

  STAGE(lds[0], t0 * 32)

  bf16x8 qf[8];
#pragma unroll
  for (int dc2 = 0; dc2 < 8; ++dc2)
    qf[dc2] = *reinterpret_cast<const bf16x8*>(
        Q + ((size_t)h * S_LEN + qpos + l31) * HEAD_DIM + dc2 * 16 + g2 * 8);

  f32x16 o[4] = {};
  float m = -1e30f, l = 0.f;

  for (int t = t0; t < t1; ++t) {
    char* buf = lds[(t - t0) & 1];
    __syncthreads();  // drains this buf's staging; all waves done with buf^1
    if (t + 1 < t1) STAGE(lds[(t - t0 + 1) & 1], (t + 1) * 32)
    const char* Kl = buf;
    const char* Vl = buf + 8192;
    const int kv0 = t * 32;

    f32x16 sc = {};
    __builtin_amdgcn_s_setprio(1);
#pragma unroll
    for (int dc2 = 0; dc2 < 8; ++dc2) {
      bf16x8 kf = *reinterpret_cast<const bf16x8*>(
          Kl + l31 * 256 + ((dc2 * 32 + g2 * 16) ^ ((l31 & 15) << 4)));
      sc = __builtin_amdgcn_mfma_f32_32x32x16_bf16(kf, qf[dc2], sc, 0, 0, 0);
    }
    __builtin_amdgcn_s_setprio(0);
    if (t == qt) {
#pragma unroll
      for (int reg = 0; reg < 16; ++reg) {
        int kv = kv0 + (reg & 3) + 8 * (reg >> 2) + 4 * g2;
        if (kv > qpos + l31) sc[reg] = -1e30f;
      }
    }
    float pm = sc[0];
#pragma unroll
    for (int i = 1; i < 16; ++i) pm = fmaxf(pm, sc[i]);
    pm = fmaxf(pm, __shfl_xor(pm, 32));
    if (!__all(pm <= m + 8.f)) {  // defer-max (T13)
      float mn = fmaxf(m, pm);
      float fac = __builtin_amdgcn_exp2f(m - mn);
#pragma unroll
      for (int dc = 0; dc < 4; ++dc) o[dc] *= fac;
      l *= fac;
      m = mn;
    }
    union { __bf16 b[16]; unsigned u[8]; } P;
    float rs = 0.f;
#pragma unroll
    for (int i = 0; i < 16; ++i) {
      float p = __builtin_amdgcn_exp2f(sc[i] - m);
      rs += p;
      P.b[i] = (__bf16)p;
    }
    rs += __shfl_xor(rs, 32);
    l += rs;
    uint4 pf[2];
#pragma unroll
    for (int c16 = 0; c16 < 2; ++c16) {
      unsigned A0 = P.u[c16 * 4], A1 = P.u[c16 * 4 + 1];
      unsigned A2 = P.u[c16 * 4 + 2], A3 = P.u[c16 * 4 + 3];
      unsigned A0x = __shfl_xor(A0, 32), A1x = __shfl_xor(A1, 32);
      unsigned A2x = __shfl_xor(A2, 32), A3x = __shfl_xor(A3, 32);
      pf[c16].x = g2 ? A2x : A0;
      pf[c16].y = g2 ? A3x : A1;
      pf[c16].z = g2 ? A2 : A0x;
      pf[c16].w = g2 ? A3 : A1x;
    }
    __builtin_amdgcn_s_setprio(1);
#pragma unroll
    for (int c16 = 0; c16 < 2; ++c16) {
      union { uint4 u; bf16x8 v; } cv;
      cv.u = pf[c16];
#pragma unroll
      for (int dc = 0; dc < 4; ++dc) {
        const int r = dc * 16 + (l31 >> 1);
        const int cu = (l31 & 1) * 64 + c16 * 32 + g2 * 16;
        bf16x8 vf = *reinterpret_cast<const bf16x8*>(Vl + r * 128 + (cu ^ ((r & 7) << 4)));
        o[dc] = __builtin_amdgcn_mfma_f32_32x32x16_bf16(vf, cv.v, o[dc], 0, 0, 0);
      }
    }
    __builtin_amdgcn_s_setprio(0);
  }

  if (g2 == 0) {
    Mh[h * 4096 + qpos + l31] = m;
    Lh[h * 4096 + qpos + l31] = l;
  }
#pragma unroll
  for (int dc = 0; dc < 4; ++dc)
#pragma unroll
    for (int reg = 0; reg < 16; ++reg) {
      int d = dc * 32 + (reg & 3) + 8 * (reg >> 2) + 4 * g2;
      Op[(((size_t)(h * 128 + d)) << 12) + qpos + l31] = f2bf(o[dc][reg]);
    }
#undef STAGE
}

// ---------------- combine the two kv-halves (m in log2 domain) ----------------
__global__ __launch_bounds__(256) void k_combine(
    const unsigned short* __restrict__ Op0, const unsigned short* __restrict__ Op1,
    const float* __restrict__ Mp, const float* __restrict__ Lp,
    unsigned short* __restrict__ AO) {
  const int idx = blockIdx.x * 256 + threadIdx.x;  // 65536 = 16 h * 4096 q
  const int h = idx >> 12, q = idx & 4095;
  const float m0 = Mp[h * 4096 + q], m1 = Mp[16 * 4096 + h * 4096 + q];
  const float l0 = Lp[h * 4096 + q], l1 = Lp[16 * 4096 + h * 4096 + q];
  const float mm = fmaxf(m0, m1);
  const float w0 = __builtin_amdgcn_exp2f(m0 - mm);
  const float w1 = __builtin_amdgcn_exp2f(m1 - mm);
  const float denom = w0 * l0 + w1 * l1;
  const float c0 = w0 / denom, c1 = w1 / denom;
  const bool has1 = (l1 > 0.f);
  const size_t bq = ((size_t)h * 128) << 12;
#pragma unroll
  for (int halfd = 0; halfd < 2; ++halfd) {
    float acc[64];
#pragma unroll
    for (int i = 0; i < 64; ++i) {
      const size_t off = bq + (((size_t)(halfd * 64 + i)) << 12) + q;
      float v = c0 * bf2f(Op0[off]);
      if (has1) v += c1 * bf2f(Op1[off]);
      acc[i] = v;
    }
#pragma unroll
    for (int dc = 0; dc < 8; ++dc) {
      union { unsigned short s[8]; uint4 u; } pk;
#pragma unroll
      for (int j = 0; j < 8; ++j) pk.s[j] = f2bf(acc[dc * 8 + j]);
      *reinterpret_cast<uint4*>(AO + (size_t)q * QDIM + h * 128 + halfd * 64 + dc * 8) = pk.u;
    }
  }
}

extern "C" void kernel_launch(void* const* d_in, const int* in_sizes, int n_in,
                              void* d_out, int out_size, void* d_ws, size_t ws_size,
                              hipStream_t stream) {
  const float* hs = (const float*)d_in[0];
  const float* wq = (const float*)d_in[1];
  const float* wk = (const float*)d_in[2];
  const float* wv = (const float*)d_in[3];
  const float* wo = (const float*)d_in[4];
  const float* qnw = (const float*)d_in[5];
  const float* knw = (const float*)d_in[6];
  float* out = (float*)d_out;

  char* base = (char*)d_ws;
  unsigned short* Xb = (unsigned short*)base;                  // 16.78 MB (dead after GEMM1)
  unsigned short* Qb = Xb;                                     // reuse
  unsigned short* Wqkv = (unsigned short*)(base + 16777216);   // 12.58 MB (dead after GEMM1)
  unsigned short* Kb = Wqkv;                                   // reuse (4.19 MB)
  unsigned short* Vtb = (unsigned short*)(base + 20971520);    // reuse (4.19 MB)
  float* Mp = (float*)(base + 25165824);                       // 512 KB
  float* Lp = (float*)(base + 25690112);                       // 512 KB
  unsigned short* Wob = (unsigned short*)(base + 29360128);    // 8.39 MB (live to end)
  unsigned short* QKVb = (unsigned short*)(base + 37748736);   // 25.17 MB bf16 (dead after norm)
  unsigned short* AOb = QKVb;                                  // reuse (16.78 MB)
  unsigned short* Op0 = (unsigned short*)(base + 54525952);    // 16.78 MB partial, half 0
  unsigned short* Op1 = (unsigned short*)(base + 71303168);    // 16.78 MB partial, half 1
  float* cosT = (float*)(base + 88080384);                     // 1 MB
  float* sinT = (float*)(base + 89128960);                     // 1 MB

  k_prep<<<2048, 256, 0, stream>>>(hs, wq, wk, wv, wo, Xb, Wqkv, Wob, cosT, sinT);
  k_gemm1<<<dim3(QKVD / 192, S_LEN / 128), 512, 0, stream>>>(Xb, Wqkv, QKVb);
  k_norm_rope<<<S_LEN, 256, 0, stream>>>(QKVb, qnw, knw, cosT, sinT, Qb, Kb, Vtb);
  k_attn<<<1024, 256, 0, stream>>>(Qb, Kb, Vtb, Op0, Op1, Mp, Lp);
  k_combine<<<256, 256, 0, stream>>>(Op0, Op1, Mp, Lp, AOb);
  k_gemm<0><<<dim3(QDIM / 128, S_LEN / 128), 256, 0, stream>>>(AOb, Wob, (void*)out, QDIM);
}